// Round 7
// baseline (1176.940 us; speedup 1.0000x reference)
//
#include <hip/hip_runtime.h>
#include <stdint.h>

// Problem constants
#define B_   8
#define N_   32768
#define C_   32
#define K_   22
#define CAT_ 40

typedef unsigned short u16;
typedef unsigned int   u32;

typedef __attribute__((ext_vector_type(8))) short bf16x8;
typedef __attribute__((ext_vector_type(4))) float f32x4;

#define MFMA(a, b, c) __builtin_amdgcn_mfma_f32_16x16x32_bf16(a, b, c, 0, 0, 0)

// ---------- bf16 helpers ----------
__device__ __forceinline__ float b2f(u16 v) { return __uint_as_float(((u32)v) << 16); }
__device__ __forceinline__ u16 f2b(float f) {
    u32 x = __float_as_uint(f);
    return (u16)((x + 0x7fffu + ((x >> 16) & 1u)) >> 16);   // RNE
}
__device__ __forceinline__ u32 pk2(float a, float b) {
    return (u32)f2b(a) | ((u32)f2b(b) << 16);
}

// ---------- packed MFMA A-fragment weight offsets (u16 units) ----------
#define PK_WIN 0
#define PK_W1  8192
#define PK_W2  40960
#define PK_W3  57344
#define PK_WC1 90112
#define PK_WC2 122880
#define PK_WC3 188416
#define PK_WO1 204800
#define PK_WO2 237568

// ---------- fp32 bias block offsets (floats) ----------
#define OBIN 0
#define OB1  256
#define OB2  384
#define OB3  640
#define OBC1 896
#define OBC2 1152
#define OBC3 1664
#define OBO1 1728
#define OBO2 1856
#define ODB1 1984
#define ODB2 2240
#define ODB3 2496

// ---------- canonical bf16 dense-head weights (u16 offsets) ----------
#define ODW1 0
#define ODW2 32768
#define ODW3 98304

// ---------- segment accumulator geometry ----------
#define SEGW 164
#define SEGSZ (32 * SEGW)

// ---------- LDS arena strides (u16) : dword-stride == 4 mod 32, rows 16B-aligned ----------
#define SBA 328   // kA0/kA1 arena: 64*328*2 = 41984 B
#define SBC 392   // kC arena:      64*392*2 = 50176 B

// ---------- workspace byte offsets ----------
#define OFS_WPK   0u
#define OFS_BIAS  524288u
#define OFS_DWC   540672u
#define OFS_MODE  786432u
#define OFS_GACC0 819200u
#define OFS_GACC1 (OFS_GACC0 + 4u*SEGSZ*8u)          // +167936
#define OFS_GNET  (OFS_GACC1 + 4u*SEGSZ*8u)
#define GACC_ZERO_BYTES (4u*SEGSZ*8u*2u + 4096u)
#define OFS_CF20  1191936u
#define OFS_CF21  1257472u
// FEATC32 aliases the F1 region: kPrep writes it, kA0 is last consumer, kA1 overwrites with f1.
#define OFS_F1    2097152u
#define OFS_FEATC 2097152u
#define OFS_F0    69206016u
// end = 136,314,880 bytes

// ---------- dtype sniffer ----------
__global__ void kSniff(const u16* __restrict__ featAny, int* __restrict__ mode) {
    __shared__ int cnt;
    if (threadIdx.x == 0) cnt = 0;
    __syncthreads();
    int weird = 0;
    for (int j = 0; j < 4; ++j) {
        u16 v = featAny[threadIdx.x * 4 + j];
        float f = b2f(v);
        if (v == 0 || !(fabsf(f) < 1e10f)) weird++;
    }
    if (weird) atomicAdd(&cnt, weird);
    __syncthreads();
    if (threadIdx.x == 0) *mode = (cnt > 64) ? 1 : 0;
}

__device__ __forceinline__ float fetchF(const void* src, size_t i, int mode) {
    return mode ? ((const float*)src)[i] : b2f(((const u16*)src)[i]);
}

// ---------- weight pack: (COUT,CIN) -> MFMA A-fragment bf16 order ----------
__device__ void packA(const void* __restrict__ src, u16* __restrict__ dst,
                      int COUT, int CIN, int mode, int tid, int np) {
    int KB = (CIN + 31) / 32;
    int tiles = COUT / 16;
    int tot = tiles * KB * 64 * 8;
    for (int i = tid; i < tot; i += np) {
        int j = i & 7;
        int L = (i >> 3) & 63;
        int rest = i >> 9;
        int kb = rest % KB, tile = rest / KB;
        int co = tile * 16 + (L & 15);
        int ci = kb * 32 + (L >> 4) * 8 + j;
        float v = (ci < CIN) ? fetchF(src, (size_t)co * CIN + ci, mode) : 0.f;
        dst[i] = f2b(v);
    }
}

__device__ void cvtF(const void* __restrict__ src, float* __restrict__ dst,
                     int n, int mode, int tid, int np) {
    for (int i = tid; i < n; i += np) dst[i] = fetchF(src, i, mode);
}

__device__ void cvtB(const void* __restrict__ src, u16* __restrict__ dst,
                     int n, int mode, int tid, int np) {
    for (int i = tid; i < n; i += np)
        dst[i] = mode ? f2b(((const float*)src)[i]) : ((const u16*)src)[i];
}

// features -> point-major 32-ch zero-padded bf16 (16B-aligned rows)
__device__ void cvtFeat(const void* __restrict__ src, u16* __restrict__ dst,
                        int mode, int tid, int np) {
    int tot = B_ * N_ * 32;
    for (int i = tid; i < tot; i += np) {
        int p = i >> 5, k = i & 31;
        u16 v = 0;
        if (k < 22)
            v = mode ? f2b(((const float*)src)[(size_t)p * 22 + k])
                     : ((const u16*)src)[(size_t)p * 22 + k];
        dst[i] = v;
    }
}

__global__ void kPrep(const void* feat, const void* w_in, const void* b_in,
                      const void* w1, const void* b1, const void* w2, const void* b2,
                      const void* w3, const void* b3,
                      const void* wc1, const void* bc1, const void* wc2, const void* bc2,
                      const void* wc3, const void* bc3,
                      const void* wo1, const void* bo1, const void* wo2, const void* bo2,
                      const void* dw1, const void* db1, const void* dw2, const void* db2,
                      const void* dw3, const void* db3,
                      u16* WPK, float* BIAS, u16* DWC, u16* FEATC,
                      const int* __restrict__ modep) {
    const int mode = *modep;
    int tid = blockIdx.x * blockDim.x + threadIdx.x;
    int np  = gridDim.x * blockDim.x;
    cvtFeat(feat, FEATC, mode, tid, np);
    packA(w_in, WPK + PK_WIN, 256, 22, mode, tid, np);
    packA(w1,                                  WPK + PK_W1,          64, 256, mode, tid, np);
    packA((const u16*)w1 + (mode?32768:16384), WPK + PK_W1 + 16384,  64, 256, mode, tid, np);
    packA(w2,                                  WPK + PK_W2,          128, 64, mode, tid, np);
    packA((const u16*)w2 + (mode?16384:8192),  WPK + PK_W2 + 8192,   128, 64, mode, tid, np);
    packA(w3,                                  WPK + PK_W3,          128, 128, mode, tid, np);
    packA((const u16*)w3 + (mode?32768:16384), WPK + PK_W3 + 16384,  128, 128, mode, tid, np);
    packA(wc1,                                 WPK + PK_WC1,         128, 128, mode, tid, np);
    packA((const u16*)wc1 + (mode?32768:16384),WPK + PK_WC1 + 16384, 128, 128, mode, tid, np);
    packA(wc2,                                 WPK + PK_WC2,         256, 128, mode, tid, np);
    packA((const u16*)wc2 + (mode?65536:32768),WPK + PK_WC2 + 32768, 256, 128, mode, tid, np);
    packA(wc3,                                 WPK + PK_WC3,         32, 256, mode, tid, np);
    packA((const u16*)wc3 + (mode?16384:8192), WPK + PK_WC3 + 8192,  32, 256, mode, tid, np);
    packA(wo1, WPK + PK_WO1, 128, 256, mode, tid, np);
    packA(wo2, WPK + PK_WO2, 128, 128, mode, tid, np);
    cvtF(b_in, BIAS + OBIN, 256, mode, tid, np);
    cvtF(b1,   BIAS + OB1,  128, mode, tid, np);
    cvtF(b2,   BIAS + OB2,  256, mode, tid, np);
    cvtF(b3,   BIAS + OB3,  256, mode, tid, np);
    cvtF(bc1,  BIAS + OBC1, 256, mode, tid, np);
    cvtF(bc2,  BIAS + OBC2, 512, mode, tid, np);
    cvtF(bc3,  BIAS + OBC3, 64,  mode, tid, np);
    cvtF(bo1,  BIAS + OBO1, 128, mode, tid, np);
    cvtF(bo2,  BIAS + OBO2, 128, mode, tid, np);
    cvtF(db1,  BIAS + ODB1, 256, mode, tid, np);
    cvtF(db2,  BIAS + ODB2, 256, mode, tid, np);
    cvtF(db3,  BIAS + ODB3, 40,  mode, tid, np);
    cvtB(dw1, DWC + ODW1, 128 * 256, mode, tid, np);
    cvtB(dw2, DWC + ODW2, 256 * 256, mode, tid, np);
    cvtB(dw3, DWC + ODW3, 256 * 40,  mode, tid, np);
}

// ========== phase-structured conv building blocks (64-pt tile, 4 waves) ==========
template<int CPW, int KBTOT, int KB, int KBOFF, int SBS>
__device__ __forceinline__ void convL(const u16* __restrict__ wA, int coTile,
                                      const u16* __restrict__ sB, int colBase,
                                      f32x4 (&acc)[CPW][4], int lane) {
    const int lp = lane & 15, q = lane >> 4;
#pragma unroll
    for (int kb = 0; kb < KB; ++kb) {
        bf16x8 bb[4];
#pragma unroll
        for (int pt = 0; pt < 4; ++pt)
            bb[pt] = *(const bf16x8*)(sB + (pt * 16 + lp) * SBS + colBase + kb * 32 + q * 8);
#pragma unroll
        for (int ct = 0; ct < CPW; ++ct) {
            bf16x8 a = *(const bf16x8*)(wA + (size_t)(((coTile + ct) * KBTOT + KBOFF + kb) * 64 + lane) * 8);
#pragma unroll
            for (int pt = 0; pt < 4; ++pt)
                acc[ct][pt] = MFMA(a, bb[pt], acc[ct][pt]);
        }
    }
}

template<int CPW, int KBTOT>
__device__ __forceinline__ void convG(const u16* __restrict__ wA, int coTile,
                                      const u16* __restrict__ gB, size_t row0,
                                      f32x4 (&acc)[CPW][4], int lane) {
    const int lp = lane & 15, q = lane >> 4;
    constexpr int CH = KBTOT * 32;
#pragma unroll
    for (int kb = 0; kb < KBTOT; ++kb) {
        bf16x8 bb[4];
#pragma unroll
        for (int pt = 0; pt < 4; ++pt)
            bb[pt] = *(const bf16x8*)(gB + (row0 + (size_t)(pt * 16 + lp)) * CH + kb * 32 + q * 8);
#pragma unroll
        for (int ct = 0; ct < CPW; ++ct) {
            bf16x8 a = *(const bf16x8*)(wA + (size_t)(((coTile + ct) * KBTOT + kb) * 64 + lane) * 8);
#pragma unroll
            for (int pt = 0; pt < 4; ++pt)
                acc[ct][pt] = MFMA(a, bb[pt], acc[ct][pt]);
        }
    }
}

template<int CPW, int SBS>
__device__ __forceinline__ void writeL(u16* __restrict__ sB, int colOff, int ltBase,
                                       const float* __restrict__ bias,
                                       f32x4 (&acc)[CPW][4], int lane) {
    const int lp = lane & 15, q = lane >> 4;
#pragma unroll
    for (int ct = 0; ct < CPW; ++ct) {
        const int ch = (ltBase + ct) * 16 + q * 4;
        f32x4 bv = *(const f32x4*)(bias + ch);
#pragma unroll
        for (int pt = 0; pt < 4; ++pt) {
            f32x4 v = acc[ct][pt];
            const int p = pt * 16 + lp;
            *(uint2*)(sB + p * SBS + colOff + ch) =
                make_uint2(pk2(fmaxf(v[0] + bv[0], 0.f), fmaxf(v[1] + bv[1], 0.f)),
                           pk2(fmaxf(v[2] + bv[2], 0.f), fmaxf(v[3] + bv[3], 0.f)));
        }
    }
}

template<int SBS>
__device__ __forceinline__ void wc3Step(const u16* __restrict__ wA, int kbOff,
                                        const u16* __restrict__ sB,
                                        f32x4 (&acc)[2], int lane, int w) {
    const int lp = lane & 15, q = lane >> 4;
#pragma unroll
    for (int kb = 0; kb < 4; ++kb) {
        bf16x8 bfrag = *(const bf16x8*)(sB + (w * 16 + lp) * SBS + kb * 32 + q * 8);
#pragma unroll
        for (int ct = 0; ct < 2; ++ct) {
            bf16x8 a = *(const bf16x8*)(wA + (size_t)((ct * 8 + kbOff + kb) * 64 + lane) * 8);
            acc[ct] = MFMA(a, bfrag, acc[ct]);
        }
    }
}

// ---------- shared tail of kA0/kA1 ----------
__device__ __forceinline__ void tileTail(u16* __restrict__ sBig, int* __restrict__ sSegC,
                                         const int* __restrict__ sClu,
                                         const u16* __restrict__ WPK, const float* __restrict__ BIAS,
                                         int wOff, int bOff,
                                         u32* __restrict__ gFo, size_t rowBase,
                                         int t, int lane, int w) {
    const int lp = lane & 15, q = lane >> 4;
    {   f32x4 acc[1][4] = {};
        convL<1, 8, 8, 0, SBA>(WPK + PK_W1 + (wOff ? 16384 : 0), w, sBig, 0, acc, lane);
        writeL<1, SBA>(sBig, 256, w, BIAS + OB1 + (bOff ? 64 : 0), acc, lane);
    }
    __syncthreads();
    {   f32x4 acc[2][4] = {};
        convL<2, 2, 2, 0, SBA>(WPK + PK_W2 + (wOff ? 8192 : 0), 2 * w, sBig, 256, acc, lane);
        writeL<2, SBA>(sBig, 0, 2 * w, BIAS + OB2 + (bOff ? 128 : 0), acc, lane);
    }
    __syncthreads();
    for (int i = t; i < 4096; i += 256) {
        int pt = i >> 6, c2 = i & 63;
        gFo[(rowBase + pt) * 64 + c2] = *(const u32*)(sBig + pt * SBA + c2 * 2);
    }
    {   f32x4 acc[2][4] = {};
        convL<2, 4, 4, 0, SBA>(WPK + PK_WC1 + (wOff ? 16384 : 0), 2 * w, sBig, 0, acc, lane);
        writeL<2, SBA>(sBig, 128, 2 * w, BIAS + OBC1 + (bOff ? 128 : 0), acc, lane);
    }
    __syncthreads();
    {   f32x4 acc[2][4] = {};
        convL<2, 4, 4, 0, SBA>(WPK + PK_WC2 + (wOff ? 32768 : 0), 2 * w, sBig, 128, acc, lane);
        writeL<2, SBA>(sBig, 0, 2 * w, BIAS + OBC2 + (bOff ? 256 : 0), acc, lane);
    }
    __syncthreads();
    f32x4 cacc[2] = {};
    wc3Step<SBA>(WPK + PK_WC3 + (wOff ? 8192 : 0), 0, sBig, cacc, lane, w);
    __syncthreads();
    {   f32x4 acc[2][4] = {};
        convL<2, 4, 4, 0, SBA>(WPK + PK_WC2 + (wOff ? 32768 : 0), 8 + 2 * w, sBig, 128, acc, lane);
        writeL<2, SBA>(sBig, 0, 2 * w, BIAS + OBC2 + (bOff ? 256 : 0) + 128, acc, lane);
    }
    __syncthreads();
    wc3Step<SBA>(WPK + PK_WC3 + (wOff ? 8192 : 0), 4, sBig, cacc, lane, w);
    {   const int p = w * 16 + lp;
        const int cl = sClu[p];
        const float* bc3 = BIAS + OBC3 + (bOff ? 32 : 0);
#pragma unroll
        for (int ct = 0; ct < 2; ++ct) {
            const int ch = ct * 16 + q * 4;
            f32x4 bv = *(const f32x4*)(bc3 + ch);
            f32x4 v = cacc[ct];
#pragma unroll
            for (int u = 0; u < 4; ++u)
                atomicMax(&sSegC[cl * 33 + ch + u], __float_as_int(fmaxf(v[u] + bv[u], 0.f)));
        }
    }
    __syncthreads();   // loop-end: protects arena + sClu + sSegC
}

// ---------- iteration-0 fused kernel ----------
__global__ __launch_bounds__(256, 3)
void kA0(const u16* __restrict__ featc, const int* __restrict__ clu0,
         const u16* __restrict__ WPK, const float* __restrict__ BIAS,
         u32* __restrict__ gF, int* __restrict__ gSeg) {
    __shared__ __attribute__((aligned(16))) u16 sBig[64 * SBA];
    __shared__ int sSegC[32 * 33];
    __shared__ int sClu[64];
    const int t = threadIdx.x, lane = t & 63, w = t >> 6;
    const int b = blockIdx.y;
    const size_t bN = (size_t)b * N_;
    for (int i = t; i < 1056; i += 256) sSegC[i] = 0;

    for (int s = 0; s < 2; ++s) {
        const int n0 = (blockIdx.x * 2 + s) * 64;
        if (t < 64) sClu[t] = clu0[bN + n0 + t];
        {   f32x4 acc[2][4] = {};
            convG<2, 1>(WPK + PK_WIN, 2 * w, featc, bN + n0, acc, lane);
            writeL<2, SBA>(sBig, 0, 2 * w, BIAS + OBIN, acc, lane);
        }
        {   f32x4 acc[2][4] = {};
            convG<2, 1>(WPK + PK_WIN, 8 + 2 * w, featc, bN + n0, acc, lane);
            writeL<2, SBA>(sBig, 128, 2 * w, BIAS + OBIN + 128, acc, lane);
        }
        __syncthreads();
        tileTail(sBig, sSegC, sClu, WPK, BIAS, 0, 0, gF, bN + n0, t, lane, w);
    }
    for (int i = t; i < 1024; i += 256) {
        int clu = i >> 5, ch = i & 31;
        int v = sSegC[clu * 33 + ch];
        if (v) atomicMax(&gSeg[b * SEGSZ + clu * SEGW + 128 + ch], v);
    }
}

// ---------- f128 segment-max kernel (memory-bound, high occupancy) ----------
__global__ __launch_bounds__(256)
void kS(const u32* __restrict__ fX, const int* __restrict__ cluX, int* __restrict__ gSeg) {
    __shared__ int sSeg[SEGSZ];
    __shared__ int sClu[512];
    const int t = threadIdx.x, b = blockIdx.y;
    const size_t bN = (size_t)b * N_;
    const int p0 = blockIdx.x * 512;
    for (int i = t; i < SEGSZ; i += 256) sSeg[i] = 0;
    for (int i = t; i < 512; i += 256) sClu[i] = cluX[bN + p0 + i];
    __syncthreads();
    for (int i = t; i < 512 * 64; i += 256) {
        int pt = i >> 6, d = i & 63;
        u32 v = fX[(bN + p0 + pt) * 64 + d];
        int base = sClu[pt] * SEGW + d * 2;
        atomicMax(&sSeg[base + 0], __float_as_int(b2f((u16)v)));
        atomicMax(&sSeg[base + 1], __float_as_int(b2f((u16)(v >> 16))));
    }
    __syncthreads();
    for (int i = t; i < 32 * 128; i += 256) {
        int clu = i >> 7, ch = i & 127;
        int v = sSeg[clu * SEGW + ch];
        if (v) atomicMax(&gSeg[b * SEGSZ + clu * SEGW + ch], v);
    }
}

// ---------- per-batch cluster math -> cf2b (bf16-packed) ----------
__global__ __launch_bounds__(256)
void kB(const int* __restrict__ gSeg, u32* __restrict__ cf2b) {
    __shared__ float sA[SEGSZ];
    __shared__ float sR[1024];
    __shared__ float sI[32];
    const int t = threadIdx.x, b = blockIdx.x;
    for (int i = t; i < SEGSZ; i += 256) sA[i] = __int_as_float(gSeg[b * SEGSZ + i]);
    __syncthreads();
    if (t < 32) {
        float s = 0.f;
        for (int j = 0; j < 32; ++j) { float v = sA[t * SEGW + 128 + j]; s = fmaf(v, v, s); }
        sI[t] = 1.f / fmaxf(sqrtf(s), 1e-12f);
    }
    __syncthreads();
    for (int i = t; i < 1024; i += 256) {
        int ca = i >> 5, cb = i & 31;
        float s = 0.f;
        for (int j = 0; j < 32; ++j)
            s = fmaf(sA[ca * SEGW + 128 + j], sA[cb * SEGW + 128 + j], s);
        sR[i] = s * sI[ca] * sI[cb];
    }
    __syncthreads();
    for (int i = t; i < 2048; i += 256) {
        int c = i >> 6, m = i & 63;
        float s0 = 0.f, s1 = 0.f;
        for (int cp = 0; cp < 32; ++cp) {
            float r = sR[cp * 32 + c];
            s0 = fmaf(sA[cp * SEGW + 2 * m + 0], r, s0);
            s1 = fmaf(sA[cp * SEGW + 2 * m + 1], r, s1);
        }
        cf2b[((size_t)b * 32 + c) * 64 + m] = pk2(s0, s1);
    }
}

// ---------- iteration-1 fused kernel ----------
__global__ __launch_bounds__(256, 3)
void kA1(const u32* __restrict__ gFp, const int* __restrict__ clu_g,
         const int* __restrict__ clu_s, const u32* __restrict__ cf2b,
         const u16* __restrict__ WPK, const float* __restrict__ BIAS,
         u32* __restrict__ gFo, int* __restrict__ gSeg) {
    __shared__ __attribute__((aligned(16))) u16 sBig[64 * SBA];
    __shared__ int sSegC[32 * 33];
    __shared__ int sClu1[64];
    const int t = threadIdx.x, lane = t & 63, w = t >> 6;
    const int b = blockIdx.y;
    const size_t bN = (size_t)b * N_;
    for (int i = t; i < 1056; i += 256) sSegC[i] = 0;

    for (int s = 0; s < 2; ++s) {
        const int n0 = (blockIdx.x * 2 + s) * 64;
        if (t < 64) sClu1[t] = clu_s[bN + n0 + t];
        {   f32x4 acc[2][4] = {};
            convG<2, 4>(WPK + PK_W3, 2 * w, (const u16*)gFp, bN + n0, acc, lane);
            writeL<2, SBA>(sBig, 0, 2 * w, BIAS + OB3, acc, lane);
        }
        // FIX (R6 bug): full 128-channel cf2 gather — 64 u32 per point
        for (int i = t; i < 4096; i += 256) {
            int pt = i >> 6, m = i & 63;
            int cl = clu_g[bN + n0 + pt];
            *(u32*)(sBig + pt * SBA + 128 + m * 2) = cf2b[((size_t)b * 32 + cl) * 64 + m];
        }
        __syncthreads();
        tileTail(sBig, sSegC, sClu1, WPK, BIAS, 1, 1, gFo, bN + n0, t, lane, w);
    }
    for (int i = t; i < 1024; i += 256) {
        int clu = i >> 5, ch = i & 31;
        int v = sSegC[clu * 33 + ch];
        if (v) atomicMax(&gSeg[b * SEGSZ + clu * SEGW + 128 + ch], v);
    }
}

// ---------- final conv head + per-channel max over points ----------
__global__ __launch_bounds__(256, 3)
void kC(const u32* __restrict__ gFp, const int* __restrict__ clu_g,
        const u32* __restrict__ cf2b,
        const u16* __restrict__ WPK, const float* __restrict__ BIAS,
        int* __restrict__ gNet) {
    __shared__ __attribute__((aligned(16))) u16 sBig[64 * SBC];
    __shared__ int sNet[128];
    const int t = threadIdx.x, lane = t & 63, w = t >> 6;
    const int lp = lane & 15, q = lane >> 4;
    const int b = blockIdx.y;
    const size_t bN = (size_t)b * N_;
    if (t < 128) sNet[t] = 0;

    for (int s = 0; s < 2; ++s) {
        const int n0 = (blockIdx.x * 2 + s) * 64;
        {   f32x4 acc[2][4] = {};
            convG<2, 4>(WPK + PK_W3 + 16384, 2 * w, (const u16*)gFp, bN + n0, acc, lane);
            writeL<2, SBC>(sBig, 0, 2 * w, BIAS + OB3 + 128, acc, lane);
        }
        // FIX (R6 bug): full 128-channel cf2 gather
        for (int i = t; i < 4096; i += 256) {
            int pt = i >> 6, m = i & 63;
            int cl = clu_g[bN + n0 + pt];
            *(u32*)(sBig + pt * SBC + 128 + m * 2) = cf2b[((size_t)b * 32 + cl) * 64 + m];
        }
        __syncthreads();
        {   f32x4 acc[2][4] = {};
            convL<2, 8, 8, 0, SBC>(WPK + PK_WO1, 2 * w, sBig, 0, acc, lane);
            writeL<2, SBC>(sBig, 256, 2 * w, BIAS + OBO1, acc, lane);
        }
        __syncthreads();
        {   f32x4 acc[2][4] = {};
            convL<2, 4, 4, 0, SBC>(WPK + PK_WO2, 2 * w, sBig, 256, acc, lane);
#pragma unroll
            for (int ct = 0; ct < 2; ++ct) {
                const int ch = (2 * w + ct) * 16 + q * 4;
                f32x4 bv = *(const f32x4*)(BIAS + OBO2 + ch);
#pragma unroll
                for (int u = 0; u < 4; ++u) {
                    float m0 = fmaxf(acc[ct][0][u], acc[ct][1][u]);
                    float m1 = fmaxf(acc[ct][2][u], acc[ct][3][u]);
                    float r = fmaxf(fmaxf(m0, m1) + bv[u], 0.f);
                    atomicMax(&sNet[ch + u], __float_as_int(r));
                }
            }
        }
        __syncthreads();   // loop-end
    }
    if (t < 128) atomicMax(&gNet[b * 128 + t], sNet[t]);
}

// ---------- tiny MLP head (dual-mode output) ----------
__global__ __launch_bounds__(256)
void kD(const int* __restrict__ gNet, const u16* __restrict__ DWC,
        const float* __restrict__ BIAS, void* __restrict__ outv,
        const int* __restrict__ modep) {
    __shared__ float sN[1024];
    __shared__ float sD1[2048];
    __shared__ float sD2[2048];
    const int mode = *modep;
    const int t = threadIdx.x;
    for (int i = t; i < 1024; i += 256) sN[i] = __int_as_float(gNet[i]);
    __syncthreads();
    for (int i = t; i < 2048; i += 256) {
        int bb = i >> 8, o = i & 255;
        float s = BIAS[ODB1 + o];
        for (int k = 0; k < 128; ++k)
            s = fmaf(sN[bb * 128 + k], b2f(DWC[ODW1 + k * 256 + o]), s);
        sD1[i] = (s >= 0.f) ? s : 0.2f * s;
    }
    __syncthreads();
    for (int i = t; i < 2048; i += 256) {
        int bb = i >> 8, o = i & 255;
        float s = BIAS[ODB2 + o];
        for (int k = 0; k < 256; ++k)
            s = fmaf(sD1[bb * 256 + k], b2f(DWC[ODW2 + k * 256 + o]), s);
        sD2[i] = (s >= 0.f) ? s : 0.2f * s;
    }
    __syncthreads();
    for (int i = t; i < 320; i += 256) {
        int bb = i / 40, o = i - bb * 40;
        float s = BIAS[ODB3 + o];
        for (int k = 0; k < 256; ++k)
            s = fmaf(sD2[bb * 256 + k], b2f(DWC[ODW3 + k * 40 + o]), s);
        if (mode) ((float*)outv)[i] = s;
        else      ((u16*)outv)[i]   = f2b(s);
    }
}

extern "C" void kernel_launch(void* const* d_in, const int* in_sizes, int n_in,
                              void* d_out, int out_size, void* d_ws, size_t ws_size,
                              hipStream_t stream) {
    const void* feat = d_in[0];
    const int* clus = (const int*)d_in[1];

    char* ws = (char*)d_ws;
    u16*   WPK   = (u16*)(ws + OFS_WPK);
    float* BIAS  = (float*)(ws + OFS_BIAS);
    u16*   DWC   = (u16*)(ws + OFS_DWC);
    int*   modep = (int*)(ws + OFS_MODE);
    u16*   FEATC = (u16*)(ws + OFS_FEATC);
    int*   seg0  = (int*)(ws + OFS_GACC0);
    int*   seg1  = (int*)(ws + OFS_GACC1);
    int*   gNet  = (int*)(ws + OFS_GNET);
    u32*   cf20  = (u32*)(ws + OFS_CF20);
    u32*   cf21  = (u32*)(ws + OFS_CF21);
    u32*   f0    = (u32*)(ws + OFS_F0);
    u32*   f1    = (u32*)(ws + OFS_F1);

    hipMemsetAsync(ws + OFS_GACC0, 0, GACC_ZERO_BYTES, stream);
    hipLaunchKernelGGL(kSniff, dim3(1), dim3(256), 0, stream, (const u16*)feat, modep);
    hipLaunchKernelGGL(kPrep, dim3(256), dim3(256), 0, stream,
                       feat, d_in[2], d_in[3], d_in[4], d_in[5], d_in[6], d_in[7],
                       d_in[8], d_in[9], d_in[10], d_in[11], d_in[12], d_in[13],
                       d_in[14], d_in[15], d_in[16], d_in[17], d_in[18], d_in[19],
                       d_in[20], d_in[21], d_in[22], d_in[23], d_in[24], d_in[25],
                       WPK, BIAS, DWC, FEATC, modep);

    const int* clu0 = clus;
    const int* clu1 = clus + (size_t)B_ * N_;
    dim3 blk(256);

    hipLaunchKernelGGL(kA0, dim3(256, 8), blk, 0, stream,
                       FEATC, clu0, WPK, BIAS, f0, seg0);
    hipLaunchKernelGGL(kS, dim3(64, 8), blk, 0, stream, f0, clu0, seg0);
    hipLaunchKernelGGL(kB, dim3(8), blk, 0, stream, seg0, cf20);
    hipLaunchKernelGGL(kA1, dim3(256, 8), blk, 0, stream,
                       f0, clu0, clu1, cf20, WPK, BIAS, f1, seg1);
    hipLaunchKernelGGL(kS, dim3(64, 8), blk, 0, stream, f1, clu1, seg1);
    hipLaunchKernelGGL(kB, dim3(8), blk, 0, stream, seg1, cf21);
    hipLaunchKernelGGL(kC, dim3(256, 8), blk, 0, stream,
                       f1, clu1, cf21, WPK, BIAS, gNet);
    hipLaunchKernelGGL(kD, dim3(1), blk, 0, stream,
                       gNet, DWC, BIAS, d_out, modep);
}

// Round 8
// 1119.103 us; speedup vs baseline: 1.0517x; 1.0517x over previous
//
#include <hip/hip_runtime.h>
#include <stdint.h>

// Problem constants
#define B_   8
#define N_   32768
#define C_   32
#define K_   22
#define CAT_ 40

typedef unsigned short u16;
typedef unsigned int   u32;

typedef __attribute__((ext_vector_type(8))) short bf16x8;
typedef __attribute__((ext_vector_type(4))) float f32x4;

#define MFMA(a, b, c) __builtin_amdgcn_mfma_f32_16x16x32_bf16(a, b, c, 0, 0, 0)

// ---------- bf16 helpers ----------
__device__ __forceinline__ float b2f(u16 v) { return __uint_as_float(((u32)v) << 16); }
__device__ __forceinline__ u16 f2b(float f) {
    u32 x = __float_as_uint(f);
    return (u16)((x + 0x7fffu + ((x >> 16) & 1u)) >> 16);   // RNE
}
__device__ __forceinline__ u32 pk2(float a, float b) {
    return (u32)f2b(a) | ((u32)f2b(b) << 16);
}

// ---------- packed MFMA A-fragment weight offsets (u16 units) ----------
#define PK_WIN 0
#define PK_W1  8192
#define PK_W2  40960
#define PK_W3  57344
#define PK_WC1 90112
#define PK_WC2 122880
#define PK_WC3 188416
#define PK_WO1 204800
#define PK_WO2 237568

// ---------- fp32 bias block offsets (floats) ----------
#define OBIN 0
#define OB1  256
#define OB2  384
#define OB3  640
#define OBC1 896
#define OBC2 1152
#define OBC3 1664
#define OBO1 1728
#define OBO2 1856
#define ODB1 1984
#define ODB2 2240
#define ODB3 2496

// ---------- canonical bf16 dense-head weights (u16 offsets) ----------
#define ODW1 0
#define ODW2 32768
#define ODW3 98304

// ---------- segment accumulator geometry ----------
#define SEGW 164
#define SEGSZ (32 * SEGW)

// ---------- LDS arena strides (u16) ----------
#define SBA 328   // kA0/kA1 arena: 64*328*2 = 41984 B
#define SBC 392   // kC arena:      64*392*2 = 50176 B

// ---------- workspace byte offsets ----------
#define OFS_WPK   0u
#define OFS_BIAS  524288u
#define OFS_DWC   540672u
#define OFS_MODE  786432u
#define OFS_GACC0 819200u
#define OFS_GACC1 (OFS_GACC0 + 4u*SEGSZ*8u)
#define OFS_GNET  (OFS_GACC1 + 4u*SEGSZ*8u)
#define GACC_ZERO_BYTES (4u*SEGSZ*8u*2u + 4096u)
#define OFS_CF20  1191936u
#define OFS_CF21  1257472u
#define OFS_F1    2097152u
#define OFS_FEATC 2097152u
#define OFS_F0    69206016u

// ---------- dtype sniffer ----------
__global__ void kSniff(const u16* __restrict__ featAny, int* __restrict__ mode) {
    __shared__ int cnt;
    if (threadIdx.x == 0) cnt = 0;
    __syncthreads();
    int weird = 0;
    for (int j = 0; j < 4; ++j) {
        u16 v = featAny[threadIdx.x * 4 + j];
        float f = b2f(v);
        if (v == 0 || !(fabsf(f) < 1e10f)) weird++;
    }
    if (weird) atomicAdd(&cnt, weird);
    __syncthreads();
    if (threadIdx.x == 0) *mode = (cnt > 64) ? 1 : 0;
}

__device__ __forceinline__ float fetchF(const void* src, size_t i, int mode) {
    return mode ? ((const float*)src)[i] : b2f(((const u16*)src)[i]);
}

// ---------- weight pack ----------
__device__ void packA(const void* __restrict__ src, u16* __restrict__ dst,
                      int COUT, int CIN, int mode, int tid, int np) {
    int KB = (CIN + 31) / 32;
    int tiles = COUT / 16;
    int tot = tiles * KB * 64 * 8;
    for (int i = tid; i < tot; i += np) {
        int j = i & 7;
        int L = (i >> 3) & 63;
        int rest = i >> 9;
        int kb = rest % KB, tile = rest / KB;
        int co = tile * 16 + (L & 15);
        int ci = kb * 32 + (L >> 4) * 8 + j;
        float v = (ci < CIN) ? fetchF(src, (size_t)co * CIN + ci, mode) : 0.f;
        dst[i] = f2b(v);
    }
}

__device__ void cvtF(const void* __restrict__ src, float* __restrict__ dst,
                     int n, int mode, int tid, int np) {
    for (int i = tid; i < n; i += np) dst[i] = fetchF(src, i, mode);
}

__device__ void cvtB(const void* __restrict__ src, u16* __restrict__ dst,
                     int n, int mode, int tid, int np) {
    for (int i = tid; i < n; i += np)
        dst[i] = mode ? f2b(((const float*)src)[i]) : ((const u16*)src)[i];
}

__device__ void cvtFeat(const void* __restrict__ src, u16* __restrict__ dst,
                        int mode, int tid, int np) {
    int tot = B_ * N_ * 32;
    for (int i = tid; i < tot; i += np) {
        int p = i >> 5, k = i & 31;
        u16 v = 0;
        if (k < 22)
            v = mode ? f2b(((const float*)src)[(size_t)p * 22 + k])
                     : ((const u16*)src)[(size_t)p * 22 + k];
        dst[i] = v;
    }
}

__global__ void kPrep(const void* feat, const void* w_in, const void* b_in,
                      const void* w1, const void* b1, const void* w2, const void* b2,
                      const void* w3, const void* b3,
                      const void* wc1, const void* bc1, const void* wc2, const void* bc2,
                      const void* wc3, const void* bc3,
                      const void* wo1, const void* bo1, const void* wo2, const void* bo2,
                      const void* dw1, const void* db1, const void* dw2, const void* db2,
                      const void* dw3, const void* db3,
                      u16* WPK, float* BIAS, u16* DWC, u16* FEATC,
                      const int* __restrict__ modep) {
    const int mode = *modep;
    int tid = blockIdx.x * blockDim.x + threadIdx.x;
    int np  = gridDim.x * blockDim.x;
    cvtFeat(feat, FEATC, mode, tid, np);
    packA(w_in, WPK + PK_WIN, 256, 22, mode, tid, np);
    packA(w1,                                  WPK + PK_W1,          64, 256, mode, tid, np);
    packA((const u16*)w1 + (mode?32768:16384), WPK + PK_W1 + 16384,  64, 256, mode, tid, np);
    packA(w2,                                  WPK + PK_W2,          128, 64, mode, tid, np);
    packA((const u16*)w2 + (mode?16384:8192),  WPK + PK_W2 + 8192,   128, 64, mode, tid, np);
    packA(w3,                                  WPK + PK_W3,          128, 128, mode, tid, np);
    packA((const u16*)w3 + (mode?32768:16384), WPK + PK_W3 + 16384,  128, 128, mode, tid, np);
    packA(wc1,                                 WPK + PK_WC1,         128, 128, mode, tid, np);
    packA((const u16*)wc1 + (mode?32768:16384),WPK + PK_WC1 + 16384, 128, 128, mode, tid, np);
    packA(wc2,                                 WPK + PK_WC2,         256, 128, mode, tid, np);
    packA((const u16*)wc2 + (mode?65536:32768),WPK + PK_WC2 + 32768, 256, 128, mode, tid, np);
    packA(wc3,                                 WPK + PK_WC3,         32, 256, mode, tid, np);
    packA((const u16*)wc3 + (mode?16384:8192), WPK + PK_WC3 + 8192,  32, 256, mode, tid, np);
    packA(wo1, WPK + PK_WO1, 128, 256, mode, tid, np);
    packA(wo2, WPK + PK_WO2, 128, 128, mode, tid, np);
    cvtF(b_in, BIAS + OBIN, 256, mode, tid, np);
    cvtF(b1,   BIAS + OB1,  128, mode, tid, np);
    cvtF(b2,   BIAS + OB2,  256, mode, tid, np);
    cvtF(b3,   BIAS + OB3,  256, mode, tid, np);
    cvtF(bc1,  BIAS + OBC1, 256, mode, tid, np);
    cvtF(bc2,  BIAS + OBC2, 512, mode, tid, np);
    cvtF(bc3,  BIAS + OBC3, 64,  mode, tid, np);
    cvtF(bo1,  BIAS + OBO1, 128, mode, tid, np);
    cvtF(bo2,  BIAS + OBO2, 128, mode, tid, np);
    cvtF(db1,  BIAS + ODB1, 256, mode, tid, np);
    cvtF(db2,  BIAS + ODB2, 256, mode, tid, np);
    cvtF(db3,  BIAS + ODB3, 40,  mode, tid, np);
    cvtB(dw1, DWC + ODW1, 128 * 256, mode, tid, np);
    cvtB(dw2, DWC + ODW2, 256 * 256, mode, tid, np);
    cvtB(dw3, DWC + ODW3, 256 * 40,  mode, tid, np);
}

// ========== phase-structured conv building blocks (64-pt tile, 4 waves) ==========
template<int CPW, int KBTOT, int KB, int KBOFF, int SBS>
__device__ __forceinline__ void convL(const u16* __restrict__ wA, int coTile,
                                      const u16* __restrict__ sB, int colBase,
                                      f32x4 (&acc)[CPW][4], int lane) {
    const int lp = lane & 15, q = lane >> 4;
#pragma unroll
    for (int kb = 0; kb < KB; ++kb) {
        bf16x8 bb[4];
#pragma unroll
        for (int pt = 0; pt < 4; ++pt)
            bb[pt] = *(const bf16x8*)(sB + (pt * 16 + lp) * SBS + colBase + kb * 32 + q * 8);
#pragma unroll
        for (int ct = 0; ct < CPW; ++ct) {
            bf16x8 a = *(const bf16x8*)(wA + (size_t)(((coTile + ct) * KBTOT + KBOFF + kb) * 64 + lane) * 8);
#pragma unroll
            for (int pt = 0; pt < 4; ++pt)
                acc[ct][pt] = MFMA(a, bb[pt], acc[ct][pt]);
        }
    }
}

template<int CPW, int SBS>
__device__ __forceinline__ void writeL(u16* __restrict__ sB, int colOff, int ltBase,
                                       const float* __restrict__ bias,
                                       f32x4 (&acc)[CPW][4], int lane) {
    const int lp = lane & 15, q = lane >> 4;
#pragma unroll
    for (int ct = 0; ct < CPW; ++ct) {
        const int ch = (ltBase + ct) * 16 + q * 4;
        f32x4 bv = *(const f32x4*)(bias + ch);
#pragma unroll
        for (int pt = 0; pt < 4; ++pt) {
            f32x4 v = acc[ct][pt];
            const int p = pt * 16 + lp;
            *(uint2*)(sB + p * SBS + colOff + ch) =
                make_uint2(pk2(fmaxf(v[0] + bv[0], 0.f), fmaxf(v[1] + bv[1], 0.f)),
                           pk2(fmaxf(v[2] + bv[2], 0.f), fmaxf(v[3] + bv[3], 0.f)));
        }
    }
}

template<int SBS>
__device__ __forceinline__ void wc3Step(const u16* __restrict__ wA, int kbOff,
                                        const u16* __restrict__ sB,
                                        f32x4 (&acc)[2], int lane, int w) {
    const int lp = lane & 15, q = lane >> 4;
#pragma unroll
    for (int kb = 0; kb < 4; ++kb) {
        bf16x8 bfrag = *(const bf16x8*)(sB + (w * 16 + lp) * SBS + kb * 32 + q * 8);
#pragma unroll
        for (int ct = 0; ct < 2; ++ct) {
            bf16x8 a = *(const bf16x8*)(wA + (size_t)((ct * 8 + kbOff + kb) * 64 + lane) * 8);
            acc[ct] = MFMA(a, bfrag, acc[ct]);
        }
    }
}

// ---------- shared tail of kA0/kA1 ----------
__device__ __forceinline__ void tileTail(u16* __restrict__ sBig, int* __restrict__ sSegC,
                                         const int* __restrict__ sClu,
                                         const u16* __restrict__ WPK, const float* __restrict__ BIAS,
                                         int wOff, int bOff,
                                         u32* __restrict__ gFo, size_t rowBase,
                                         int t, int lane, int w) {
    const int lp = lane & 15, q = lane >> 4;
    {   f32x4 acc[1][4] = {};
        convL<1, 8, 8, 0, SBA>(WPK + PK_W1 + (wOff ? 16384 : 0), w, sBig, 0, acc, lane);
        writeL<1, SBA>(sBig, 256, w, BIAS + OB1 + (bOff ? 64 : 0), acc, lane);
    }
    __syncthreads();
    {   f32x4 acc[2][4] = {};
        convL<2, 2, 2, 0, SBA>(WPK + PK_W2 + (wOff ? 8192 : 0), 2 * w, sBig, 256, acc, lane);
        writeL<2, SBA>(sBig, 0, 2 * w, BIAS + OB2 + (bOff ? 128 : 0), acc, lane);
    }
    __syncthreads();
    for (int i = t; i < 4096; i += 256) {
        int pt = i >> 6, c2 = i & 63;
        gFo[(rowBase + pt) * 64 + c2] = *(const u32*)(sBig + pt * SBA + c2 * 2);
    }
    {   f32x4 acc[2][4] = {};
        convL<2, 4, 4, 0, SBA>(WPK + PK_WC1 + (wOff ? 16384 : 0), 2 * w, sBig, 0, acc, lane);
        writeL<2, SBA>(sBig, 128, 2 * w, BIAS + OBC1 + (bOff ? 128 : 0), acc, lane);
    }
    __syncthreads();
    {   f32x4 acc[2][4] = {};
        convL<2, 4, 4, 0, SBA>(WPK + PK_WC2 + (wOff ? 32768 : 0), 2 * w, sBig, 128, acc, lane);
        writeL<2, SBA>(sBig, 0, 2 * w, BIAS + OBC2 + (bOff ? 256 : 0), acc, lane);
    }
    __syncthreads();
    f32x4 cacc[2] = {};
    wc3Step<SBA>(WPK + PK_WC3 + (wOff ? 8192 : 0), 0, sBig, cacc, lane, w);
    __syncthreads();
    {   f32x4 acc[2][4] = {};
        convL<2, 4, 4, 0, SBA>(WPK + PK_WC2 + (wOff ? 32768 : 0), 8 + 2 * w, sBig, 128, acc, lane);
        writeL<2, SBA>(sBig, 0, 2 * w, BIAS + OBC2 + (bOff ? 256 : 0) + 128, acc, lane);
    }
    __syncthreads();
    wc3Step<SBA>(WPK + PK_WC3 + (wOff ? 8192 : 0), 4, sBig, cacc, lane, w);
    {   const int p = w * 16 + lp;
        const int cl = sClu[p];
        const float* bc3 = BIAS + OBC3 + (bOff ? 32 : 0);
#pragma unroll
        for (int ct = 0; ct < 2; ++ct) {
            const int ch = ct * 16 + q * 4;
            f32x4 bv = *(const f32x4*)(bc3 + ch);
            f32x4 v = cacc[ct];
#pragma unroll
            for (int u = 0; u < 4; ++u)
                atomicMax(&sSegC[cl * 33 + ch + u], __float_as_int(fmaxf(v[u] + bv[u], 0.f)));
        }
    }
    __syncthreads();   // loop-end
}

// ---------- iteration-0 fused kernel ----------
__global__ __launch_bounds__(256, 3)
void kA0(const u16* __restrict__ featc, const int* __restrict__ clu0,
         const u16* __restrict__ WPK, const float* __restrict__ BIAS,
         u32* __restrict__ gF, int* __restrict__ gSeg) {
    __shared__ __attribute__((aligned(16))) u16 sBig[64 * SBA];
    __shared__ int sSegC[32 * 33];
    __shared__ int sClu[64];
    const int t = threadIdx.x, lane = t & 63, w = t >> 6;
    const int b = blockIdx.y;
    const size_t bN = (size_t)b * N_;
    for (int i = t; i < 1056; i += 256) sSegC[i] = 0;

    for (int s = 0; s < 2; ++s) {
        const int n0 = (blockIdx.x * 2 + s) * 64;
        // stage feat (32 u16/pt) -> arena cols 256..288 (dead h region), coalesced
        for (int i = t; i < 1024; i += 256) {
            int pt = i >> 4, m = i & 15;
            *(u32*)(sBig + pt * SBA + 256 + m * 2) =
                ((const u32*)featc)[(bN + n0 + pt) * 16 + m];
        }
        if (t < 64) sClu[t] = clu0[bN + n0 + t];
        __syncthreads();
        {   f32x4 acc[2][4] = {};
            convL<2, 1, 1, 0, SBA>(WPK + PK_WIN, 2 * w, sBig, 256, acc, lane);
            writeL<2, SBA>(sBig, 0, 2 * w, BIAS + OBIN, acc, lane);
        }
        {   f32x4 acc[2][4] = {};
            convL<2, 1, 1, 0, SBA>(WPK + PK_WIN, 8 + 2 * w, sBig, 256, acc, lane);
            writeL<2, SBA>(sBig, 128, 2 * w, BIAS + OBIN + 128, acc, lane);
        }
        __syncthreads();
        tileTail(sBig, sSegC, sClu, WPK, BIAS, 0, 0, gF, bN + n0, t, lane, w);
    }
    for (int i = t; i < 1024; i += 256) {
        int clu = i >> 5, ch = i & 31;
        int v = sSegC[clu * 33 + ch];
        if (v) atomicMax(&gSeg[b * SEGSZ + clu * SEGW + 128 + ch], v);
    }
}

// ---------- f128 segment-max kernel ----------
__global__ __launch_bounds__(256)
void kS(const u32* __restrict__ fX, const int* __restrict__ cluX, int* __restrict__ gSeg) {
    __shared__ int sSeg[SEGSZ];
    __shared__ int sClu[512];
    const int t = threadIdx.x, b = blockIdx.y;
    const size_t bN = (size_t)b * N_;
    const int p0 = blockIdx.x * 512;
    for (int i = t; i < SEGSZ; i += 256) sSeg[i] = 0;
    for (int i = t; i < 512; i += 256) sClu[i] = cluX[bN + p0 + i];
    __syncthreads();
    for (int i = t; i < 512 * 64; i += 256) {
        int pt = i >> 6, d = i & 63;
        u32 v = fX[(bN + p0 + pt) * 64 + d];
        int base = sClu[pt] * SEGW + d * 2;
        atomicMax(&sSeg[base + 0], __float_as_int(b2f((u16)v)));
        atomicMax(&sSeg[base + 1], __float_as_int(b2f((u16)(v >> 16))));
    }
    __syncthreads();
    for (int i = t; i < 32 * 128; i += 256) {
        int clu = i >> 7, ch = i & 127;
        int v = sSeg[clu * SEGW + ch];
        if (v) atomicMax(&gSeg[b * SEGSZ + clu * SEGW + ch], v);
    }
}

// ---------- per-batch cluster math -> cf2b (bf16-packed) ----------
__global__ __launch_bounds__(256)
void kB(const int* __restrict__ gSeg, u32* __restrict__ cf2b) {
    __shared__ float sA[SEGSZ];
    __shared__ float sR[1024];
    __shared__ float sI[32];
    const int t = threadIdx.x, b = blockIdx.x;
    for (int i = t; i < SEGSZ; i += 256) sA[i] = __int_as_float(gSeg[b * SEGSZ + i]);
    __syncthreads();
    if (t < 32) {
        float s = 0.f;
        for (int j = 0; j < 32; ++j) { float v = sA[t * SEGW + 128 + j]; s = fmaf(v, v, s); }
        sI[t] = 1.f / fmaxf(sqrtf(s), 1e-12f);
    }
    __syncthreads();
    for (int i = t; i < 1024; i += 256) {
        int ca = i >> 5, cb = i & 31;
        float s = 0.f;
        for (int j = 0; j < 32; ++j)
            s = fmaf(sA[ca * SEGW + 128 + j], sA[cb * SEGW + 128 + j], s);
        sR[i] = s * sI[ca] * sI[cb];
    }
    __syncthreads();
    for (int i = t; i < 2048; i += 256) {
        int c = i >> 6, m = i & 63;
        float s0 = 0.f, s1 = 0.f;
        for (int cp = 0; cp < 32; ++cp) {
            float r = sR[cp * 32 + c];
            s0 = fmaf(sA[cp * SEGW + 2 * m + 0], r, s0);
            s1 = fmaf(sA[cp * SEGW + 2 * m + 1], r, s1);
        }
        cf2b[((size_t)b * 32 + c) * 64 + m] = pk2(s0, s1);
    }
}

// ---------- iteration-1 fused kernel ----------
__global__ __launch_bounds__(256, 3)
void kA1(const u32* __restrict__ gFp, const int* __restrict__ clu_g,
         const int* __restrict__ clu_s, const u32* __restrict__ cf2b,
         const u16* __restrict__ WPK, const float* __restrict__ BIAS,
         u32* __restrict__ gFo, int* __restrict__ gSeg) {
    __shared__ __attribute__((aligned(16))) u16 sBig[64 * SBA];
    __shared__ int sSegC[32 * 33];
    __shared__ int sClu1[64];
    const int t = threadIdx.x, lane = t & 63, w = t >> 6;
    const int b = blockIdx.y;
    const size_t bN = (size_t)b * N_;
    for (int i = t; i < 1056; i += 256) sSegC[i] = 0;

    for (int s = 0; s < 2; ++s) {
        const int n0 = (blockIdx.x * 2 + s) * 64;
        // stage f128 -> arena cols 128..256 (cf2 region, currently dead), coalesced
        for (int i = t; i < 4096; i += 256) {
            int pt = i >> 6, m = i & 63;
            *(u32*)(sBig + pt * SBA + 128 + m * 2) = gFp[(bN + n0 + pt) * 64 + m];
        }
        if (t < 64) sClu1[t] = clu_s[bN + n0 + t];
        __syncthreads();
        // w3 conv: read staged f128 (cols 128..256) -> write cols 0..128
        {   f32x4 acc[2][4] = {};
            convL<2, 4, 4, 0, SBA>(WPK + PK_W3, 2 * w, sBig, 128, acc, lane);
            writeL<2, SBA>(sBig, 0, 2 * w, BIAS + OB3, acc, lane);
        }
        __syncthreads();
        // cf2 gather overwrites dead staging (cols 128..256)
        for (int i = t; i < 4096; i += 256) {
            int pt = i >> 6, m = i & 63;
            int cl = clu_g[bN + n0 + pt];
            *(u32*)(sBig + pt * SBA + 128 + m * 2) = cf2b[((size_t)b * 32 + cl) * 64 + m];
        }
        __syncthreads();
        tileTail(sBig, sSegC, sClu1, WPK, BIAS, 1, 1, gFo, bN + n0, t, lane, w);
    }
    for (int i = t; i < 1024; i += 256) {
        int clu = i >> 5, ch = i & 31;
        int v = sSegC[clu * 33 + ch];
        if (v) atomicMax(&gSeg[b * SEGSZ + clu * SEGW + 128 + ch], v);
    }
}

// ---------- final conv head + per-channel max over points ----------
__global__ __launch_bounds__(256, 3)
void kC(const u32* __restrict__ gFp, const int* __restrict__ clu_g,
        const u32* __restrict__ cf2b,
        const u16* __restrict__ WPK, const float* __restrict__ BIAS,
        int* __restrict__ gNet) {
    __shared__ __attribute__((aligned(16))) u16 sBig[64 * SBC];
    __shared__ int sNet[128];
    const int t = threadIdx.x, lane = t & 63, w = t >> 6;
    const int lp = lane & 15, q = lane >> 4;
    const int b = blockIdx.y;
    const size_t bN = (size_t)b * N_;
    if (t < 128) sNet[t] = 0;

    for (int s = 0; s < 2; ++s) {
        const int n0 = (blockIdx.x * 2 + s) * 64;
        // stage f128 -> cols 128..256
        for (int i = t; i < 4096; i += 256) {
            int pt = i >> 6, m = i & 63;
            *(u32*)(sBig + pt * SBC + 128 + m * 2) = gFp[(bN + n0 + pt) * 64 + m];
        }
        __syncthreads();
        {   f32x4 acc[2][4] = {};
            convL<2, 4, 4, 0, SBC>(WPK + PK_W3 + 16384, 2 * w, sBig, 128, acc, lane);
            writeL<2, SBC>(sBig, 0, 2 * w, BIAS + OB3 + 128, acc, lane);
        }
        __syncthreads();
        for (int i = t; i < 4096; i += 256) {
            int pt = i >> 6, m = i & 63;
            int cl = clu_g[bN + n0 + pt];
            *(u32*)(sBig + pt * SBC + 128 + m * 2) = cf2b[((size_t)b * 32 + cl) * 64 + m];
        }
        __syncthreads();
        {   f32x4 acc[2][4] = {};
            convL<2, 8, 8, 0, SBC>(WPK + PK_WO1, 2 * w, sBig, 0, acc, lane);
            writeL<2, SBC>(sBig, 256, 2 * w, BIAS + OBO1, acc, lane);
        }
        __syncthreads();
        {   f32x4 acc[2][4] = {};
            convL<2, 4, 4, 0, SBC>(WPK + PK_WO2, 2 * w, sBig, 256, acc, lane);
#pragma unroll
            for (int ct = 0; ct < 2; ++ct) {
                const int ch = (2 * w + ct) * 16 + q * 4;
                f32x4 bv = *(const f32x4*)(BIAS + OBO2 + ch);
#pragma unroll
                for (int u = 0; u < 4; ++u) {
                    float m0 = fmaxf(acc[ct][0][u], acc[ct][1][u]);
                    float m1 = fmaxf(acc[ct][2][u], acc[ct][3][u]);
                    float r = fmaxf(fmaxf(m0, m1) + bv[u], 0.f);
                    atomicMax(&sNet[ch + u], __float_as_int(r));
                }
            }
        }
        __syncthreads();   // loop-end
    }
    if (t < 128) atomicMax(&gNet[b * 128 + t], sNet[t]);
}

// ---------- tiny MLP head ----------
__global__ __launch_bounds__(256)
void kD(const int* __restrict__ gNet, const u16* __restrict__ DWC,
        const float* __restrict__ BIAS, void* __restrict__ outv,
        const int* __restrict__ modep) {
    __shared__ float sN[1024];
    __shared__ float sD1[2048];
    __shared__ float sD2[2048];
    const int mode = *modep;
    const int t = threadIdx.x;
    for (int i = t; i < 1024; i += 256) sN[i] = __int_as_float(gNet[i]);
    __syncthreads();
    for (int i = t; i < 2048; i += 256) {
        int bb = i >> 8, o = i & 255;
        float s = BIAS[ODB1 + o];
        for (int k = 0; k < 128; ++k)
            s = fmaf(sN[bb * 128 + k], b2f(DWC[ODW1 + k * 256 + o]), s);
        sD1[i] = (s >= 0.f) ? s : 0.2f * s;
    }
    __syncthreads();
    for (int i = t; i < 2048; i += 256) {
        int bb = i >> 8, o = i & 255;
        float s = BIAS[ODB2 + o];
        for (int k = 0; k < 256; ++k)
            s = fmaf(sD1[bb * 256 + k], b2f(DWC[ODW2 + k * 256 + o]), s);
        sD2[i] = (s >= 0.f) ? s : 0.2f * s;
    }
    __syncthreads();
    for (int i = t; i < 320; i += 256) {
        int bb = i / 40, o = i - bb * 40;
        float s = BIAS[ODB3 + o];
        for (int k = 0; k < 256; ++k)
            s = fmaf(sD2[bb * 256 + k], b2f(DWC[ODW3 + k * 40 + o]), s);
        if (mode) ((float*)outv)[i] = s;
        else      ((u16*)outv)[i]   = f2b(s);
    }
}

extern "C" void kernel_launch(void* const* d_in, const int* in_sizes, int n_in,
                              void* d_out, int out_size, void* d_ws, size_t ws_size,
                              hipStream_t stream) {
    const void* feat = d_in[0];
    const int* clus = (const int*)d_in[1];

    char* ws = (char*)d_ws;
    u16*   WPK   = (u16*)(ws + OFS_WPK);
    float* BIAS  = (float*)(ws + OFS_BIAS);
    u16*   DWC   = (u16*)(ws + OFS_DWC);
    int*   modep = (int*)(ws + OFS_MODE);
    u16*   FEATC = (u16*)(ws + OFS_FEATC);
    int*   seg0  = (int*)(ws + OFS_GACC0);
    int*   seg1  = (int*)(ws + OFS_GACC1);
    int*   gNet  = (int*)(ws + OFS_GNET);
    u32*   cf20  = (u32*)(ws + OFS_CF20);
    u32*   cf21  = (u32*)(ws + OFS_CF21);
    u32*   f0    = (u32*)(ws + OFS_F0);
    u32*   f1    = (u32*)(ws + OFS_F1);

    hipMemsetAsync(ws + OFS_GACC0, 0, GACC_ZERO_BYTES, stream);
    hipLaunchKernelGGL(kSniff, dim3(1), dim3(256), 0, stream, (const u16*)feat, modep);
    hipLaunchKernelGGL(kPrep, dim3(256), dim3(256), 0, stream,
                       feat, d_in[2], d_in[3], d_in[4], d_in[5], d_in[6], d_in[7],
                       d_in[8], d_in[9], d_in[10], d_in[11], d_in[12], d_in[13],
                       d_in[14], d_in[15], d_in[16], d_in[17], d_in[18], d_in[19],
                       d_in[20], d_in[21], d_in[22], d_in[23], d_in[24], d_in[25],
                       WPK, BIAS, DWC, FEATC, modep);

    const int* clu0 = clus;
    const int* clu1 = clus + (size_t)B_ * N_;
    dim3 blk(256);

    hipLaunchKernelGGL(kA0, dim3(256, 8), blk, 0, stream,
                       FEATC, clu0, WPK, BIAS, f0, seg0);
    hipLaunchKernelGGL(kS, dim3(64, 8), blk, 0, stream, f0, clu0, seg0);
    hipLaunchKernelGGL(kB, dim3(8), blk, 0, stream, seg0, cf20);
    hipLaunchKernelGGL(kA1, dim3(256, 8), blk, 0, stream,
                       f0, clu0, clu1, cf20, WPK, BIAS, f1, seg1);
    hipLaunchKernelGGL(kS, dim3(64, 8), blk, 0, stream, f1, clu1, seg1);
    hipLaunchKernelGGL(kB, dim3(8), blk, 0, stream, seg1, cf21);
    hipLaunchKernelGGL(kC, dim3(256, 8), blk, 0, stream,
                       f1, clu1, cf21, WPK, BIAS, gNet);
    hipLaunchKernelGGL(kD, dim3(1), blk, 0, stream,
                       gNet, DWC, BIAS, d_out, modep);
}